// Round 18
// baseline (371.886 us; speedup 1.0000x reference)
//
#include <hip/hip_runtime.h>

#define SEQ   512
#define IN    28
#define HID   128
#define NCLS  10
#define MB    16        // batch rows per block -> 32 blocks
#define PCH   160       // LDS pitch bytes (R14/R17: halves bank conflicts vs 144)
#define MAGICF 12582912.0f   // 1.5 * 2^23

typedef __attribute__((ext_vector_type(4))) int   i32x4;
typedef __attribute__((ext_vector_type(4))) float f32x4;
typedef __attribute__((ext_vector_type(8))) short short8v;

// h = a/127 ; W = wa/1024 + wb/262144 ; (aa<<8)+cr scale = 1/(127*1024*256)
#define SH_CR (1.0f/33292288.0f)

__device__ __forceinline__ unsigned short f2bf(float f) {
    unsigned u = __float_as_uint(f);
    return (unsigned short)((u + 0x7FFFu + ((u >> 16) & 1u)) >> 16);   // RNE
}
__device__ __forceinline__ unsigned cvtpk(float a, float b) {
    unsigned r;
    asm("v_cvt_pk_bf16_f32 %0, %1, %2" : "=v"(r) : "v"(a), "v"(b));
    return r;
}
__device__ __forceinline__ float fast_tanh(float x) {
    float e = exp2f(x * 2.8853900817779268f);   // e^(2x) via v_exp_f32
    return 1.0f - 2.0f * __builtin_amdgcn_rcpf(e + 1.0f);
}
__device__ __forceinline__ f32x4 mfma_bf(short8v a, short8v b, f32x4 c) {
    return __builtin_amdgcn_mfma_f32_16x16x32_bf16(a, b, c, 0, 0, 0);
}
__device__ __forceinline__ i32x4 mfma_i8(i32x4 a, i32x4 b, i32x4 c) {
    return __builtin_amdgcn_mfma_i32_16x16x64_i8(a, b, c, 0, 0, 0);
}
__device__ __forceinline__ void quantW(float wv, signed char& qa, signed char& qb) {
    int a = (int)rintf(wv * 1024.0f);
    float r = fmaf((float)a, -1.0f / 1024.0f, wv);
    int b = (int)rintf(r * 262144.0f);
    b = b > 127 ? 127 : (b < -127 ? -127 : b);
    qa = (signed char)a;
    qb = (signed char)b;
}
// 1-term magic quantize -> packed signed bytes via v_perm
__device__ __forceinline__ unsigned quant4a(float t0, float t1, float t2, float t3) {
    unsigned u0 = __float_as_uint(fmaf(t0, 127.0f, MAGICF));
    unsigned u1 = __float_as_uint(fmaf(t1, 127.0f, MAGICF));
    unsigned u2 = __float_as_uint(fmaf(t2, 127.0f, MAGICF));
    unsigned u3 = __float_as_uint(fmaf(t3, 127.0f, MAGICF));
    unsigned t01 = __builtin_amdgcn_perm(u1, u0, 0x00000400u);
    unsigned t23 = __builtin_amdgcn_perm(u3, u2, 0x00000400u);
    return __builtin_amdgcn_perm(t23, t01, 0x05040100u);
}

union FragI8 { i32x4 v; signed char c[16]; };
union FragBF { short8v s; unsigned u[4]; };

__global__ __launch_bounds__(1024)
void rnn2_i8x(const float* __restrict__ x,
              const float* __restrict__ W_ih0, const float* __restrict__ W_hh0,
              const float* __restrict__ b_ih0, const float* __restrict__ b_hh0,
              const float* __restrict__ W_ih1, const float* __restrict__ W_hh1,
              const float* __restrict__ b_ih1, const float* __restrict__ b_hh1,
              const float* __restrict__ W_fc,  const float* __restrict__ b_fc,
              float* __restrict__ out)
{
    // h state: [layer][buf][batch row * PCH] (i8 a-term, [batch][unit])
    __shared__ __attribute__((aligned(16))) signed char hmem[2][2][MB * PCH];
    __shared__ float hfin[MB][HID + 4];   // exact f32 h1(511) for the fc

    const int t    = threadIdx.x;   // 0..1023 (16 waves)
    const int lane = t & 63;
    const int w    = t >> 6;        // waves 0-7: L0 (tile w); waves 8-15: L1 (tile w-8)
    const int lm   = lane & 15;
    const int lg   = lane >> 4;
    const int b0   = blockIdx.x * MB;
    const bool isL0 = (w < 8);
    const int T    = isL0 ? w : (w - 8);
    const int j    = 16 * T + lm;

    // ---- role-specific persistent weight fragments (A[m=lm][k=64kt+16lg+e])
    i32x4 Wa[2][2], Wb[2][2];      // L0: [0]=Whh0 ; L1: [0]=Wih1, [1]=Whh1
    short8v WxH = {};              // L0: W_ih0 single-term bf16
    float biasv[4];

    if (isL0) {
        #pragma unroll
        for (int kt = 0; kt < 2; ++kt) {
            const float* p = W_hh0 + j * HID + 64 * kt + 16 * lg;
            FragI8 a, b;
            #pragma unroll
            for (int e = 0; e < 16; ++e) quantW(p[e], a.c[e], b.c[e]);
            Wa[0][kt] = a.v; Wb[0][kt] = b.v;
        }
        FragBF H;
        #pragma unroll
        for (int p = 0; p < 4; ++p) {
            const int k0 = 8 * lg + 2 * p, k1 = k0 + 1;
            float w0 = (k0 < IN) ? W_ih0[j * IN + k0] : 0.0f;
            float w1 = (k1 < IN) ? W_ih0[j * IN + k1] : 0.0f;
            H.u[p] = (unsigned)f2bf(w0) | ((unsigned)f2bf(w1) << 16);
        }
        WxH = H.s;
        #pragma unroll
        for (int r = 0; r < 4; ++r) {
            const int u = 16 * T + 4 * lg + r;
            biasv[r] = b_ih0[u] + b_hh0[u];
        }
    } else {
        #pragma unroll
        for (int kt = 0; kt < 2; ++kt) {
            const float* p1 = W_ih1 + j * HID + 64 * kt + 16 * lg;
            const float* p2 = W_hh1 + j * HID + 64 * kt + 16 * lg;
            FragI8 a1, q1, a2, q2;
            #pragma unroll
            for (int e = 0; e < 16; ++e) {
                quantW(p1[e], a1.c[e], q1.c[e]);
                quantW(p2[e], a2.c[e], q2.c[e]);
            }
            Wa[0][kt] = a1.v; Wb[0][kt] = q1.v;
            Wa[1][kt] = a2.v; Wb[1][kt] = q2.v;
        }
        #pragma unroll
        for (int r = 0; r < 4; ++r) {
            const int u = 16 * T + 4 * lg + r;
            biasv[r] = b_ih1[u] + b_hh1[u];
        }
    }

    // ---- zero LDS h-state (both buffers)
    {
        int* z = (int*)&hmem[0][0][0];
        #pragma unroll
        for (int i = 0; i < 3; ++i) {
            const int idx = t + i * 1024;
            if (idx < (int)(sizeof(hmem) / 4)) z[idx] = 0;
        }
    }

    const int rbase = lm * PCH + 16 * lg;
    const int wbase = lm * PCH + 16 * T + 4 * lg;
    const i32x4 z4 = {0, 0, 0, 0};

    // ---- x double-buffered register sets (L0 only); E = even timestep, O = odd
    const float* xptr = x + ((size_t)(b0 + lm) * SEQ) * IN + 8 * lg;
    float4 xEA = make_float4(0.f, 0.f, 0.f, 0.f), xEB = xEA;
    float4 xOA = xEA, xOB = xEA;

    auto loadx = [&](const float* p, float4& a, float4& b) {
        a = *(const float4*)p;
        b = make_float4(0.f, 0.f, 0.f, 0.f);
        if (lg < 3) b = *(const float4*)(p + 4);
    };

    // L0 body: h0 recurrence step. RB/WB are literal buffer indices after inlining.
    auto l0_body = [&](int RB, int WB, const float4& xa, const float4& xb) {
        i32x4 Ba0, Ba1;
        Ba0 = *(const i32x4*)&hmem[0][RB][rbase];
        Ba1 = *(const i32x4*)&hmem[0][RB][rbase + 64];
        FragBF H;
        H.u[0] = cvtpk(xa.x, xa.y);
        H.u[1] = cvtpk(xa.z, xa.w);
        H.u[2] = cvtpk(xb.x, xb.y);
        H.u[3] = cvtpk(xb.z, xb.w);
        __builtin_amdgcn_s_setprio(1);
        f32x4 accx = {biasv[0], biasv[1], biasv[2], biasv[3]};
        accx = mfma_bf(WxH, H.s, accx);
        i32x4 aa = mfma_i8(Wa[0][0], Ba0, z4);
        aa = mfma_i8(Wa[0][1], Ba1, aa);
        i32x4 cr = mfma_i8(Wb[0][0], Ba0, z4);
        cr = mfma_i8(Wb[0][1], Ba1, cr);
        __builtin_amdgcn_s_setprio(0);
        float t0 = fast_tanh(fmaf((float)((aa[0] << 8) + cr[0]), SH_CR, accx[0]));
        float t1 = fast_tanh(fmaf((float)((aa[1] << 8) + cr[1]), SH_CR, accx[1]));
        float t2 = fast_tanh(fmaf((float)((aa[2] << 8) + cr[2]), SH_CR, accx[2]));
        float t3 = fast_tanh(fmaf((float)((aa[3] << 8) + cr[3]), SH_CR, accx[3]));
        *(unsigned*)&hmem[0][WB][wbase] = quant4a(t0, t1, t2, t3);
    };

    // L1 body: h1 recurrence step (consumes h0 and h1 from buf RB).
    auto l1_body = [&](int RB, int WB) {
        i32x4 Ba0, Ba1, Bb0, Bb1;
        Ba0 = *(const i32x4*)&hmem[0][RB][rbase];
        Ba1 = *(const i32x4*)&hmem[0][RB][rbase + 64];
        Bb0 = *(const i32x4*)&hmem[1][RB][rbase];
        Bb1 = *(const i32x4*)&hmem[1][RB][rbase + 64];
        __builtin_amdgcn_s_setprio(1);
        i32x4 aa = mfma_i8(Wa[0][0], Ba0, z4);
        aa = mfma_i8(Wa[0][1], Ba1, aa);
        aa = mfma_i8(Wa[1][0], Bb0, aa);
        aa = mfma_i8(Wa[1][1], Bb1, aa);
        i32x4 cr = mfma_i8(Wb[0][0], Ba0, z4);
        cr = mfma_i8(Wb[0][1], Ba1, cr);
        cr = mfma_i8(Wb[1][0], Bb0, cr);
        cr = mfma_i8(Wb[1][1], Bb1, cr);
        __builtin_amdgcn_s_setprio(0);
        float t0 = fast_tanh(fmaf((float)((aa[0] << 8) + cr[0]), SH_CR, biasv[0]));
        float t1 = fast_tanh(fmaf((float)((aa[1] << 8) + cr[1]), SH_CR, biasv[1]));
        float t2 = fast_tanh(fmaf((float)((aa[2] << 8) + cr[2]), SH_CR, biasv[2]));
        float t3 = fast_tanh(fmaf((float)((aa[3] << 8) + cr[3]), SH_CR, biasv[3]));
        *(unsigned*)&hmem[1][WB][wbase] = quant4a(t0, t1, t2, t3);
    };

    // final L1 step: exact f32 h1(511) -> hfin (no quantize, no hmem write)
    auto l1_final = [&](int RB) {
        i32x4 Ba0, Ba1, Bb0, Bb1;
        Ba0 = *(const i32x4*)&hmem[0][RB][rbase];
        Ba1 = *(const i32x4*)&hmem[0][RB][rbase + 64];
        Bb0 = *(const i32x4*)&hmem[1][RB][rbase];
        Bb1 = *(const i32x4*)&hmem[1][RB][rbase + 64];
        i32x4 aa = mfma_i8(Wa[0][0], Ba0, z4);
        aa = mfma_i8(Wa[0][1], Ba1, aa);
        aa = mfma_i8(Wa[1][0], Bb0, aa);
        aa = mfma_i8(Wa[1][1], Bb1, aa);
        i32x4 cr = mfma_i8(Wb[0][0], Ba0, z4);
        cr = mfma_i8(Wb[0][1], Ba1, cr);
        cr = mfma_i8(Wb[1][0], Bb0, cr);
        cr = mfma_i8(Wb[1][1], Bb1, cr);
        const int u = 16 * T + 4 * lg;
        hfin[lm][u + 0] = fast_tanh(fmaf((float)((aa[0] << 8) + cr[0]), SH_CR, biasv[0]));
        hfin[lm][u + 1] = fast_tanh(fmaf((float)((aa[1] << 8) + cr[1]), SH_CR, biasv[1]));
        hfin[lm][u + 2] = fast_tanh(fmaf((float)((aa[2] << 8) + cr[2]), SH_CR, biasv[2]));
        hfin[lm][u + 3] = fast_tanh(fmaf((float)((aa[3] << 8) + cr[3]), SH_CR, biasv[3]));
    };

    if (isL0) loadx(xptr, xEA, xEB);   // x(0)
    __syncthreads();                   // covers LDS zero-init too

    // ---- peel it=0: L0 computes h0(0) (reads zeroed buf0, writes buf1).
    //      L1 has nothing to do: h1(-1)=h1(-2)=0 already in both buffers.
    if (isL0) {
        loadx(xptr + IN, xOA, xOB);    // prefetch x(1)
        l0_body(0, 1, xEA, xEB);
    }
    __syncthreads();

    // ---- main pairs: it = 2p+1 (rd=1) and it = 2p+2 (rd=0), p = 0..254 (it=1..510)
    for (int p = 0; p < 255; ++p) {
        if (isL0) {
            loadx(xptr + 2 * IN, xEA, xEB);   // prefetch x(2p+2)
            l0_body(1, 0, xOA, xOB);          // it=2p+1 uses x(2p+1)
        } else {
            l1_body(1, 0);                    // h1(2p)
        }
        __syncthreads();
        if (isL0) {
            loadx(xptr + 3 * IN, xOA, xOB);   // prefetch x(2p+3)
            l0_body(0, 1, xEA, xEB);          // it=2p+2 uses x(2p+2)
            xptr += 2 * IN;
        } else {
            l1_body(0, 1);                    // h1(2p+1)
        }
        __syncthreads();
    }

    // ---- peel it=511 (rd=1): L0 -> h0(511) (uses x(511) in O regs); L1 -> h1(510)
    if (isL0) l0_body(1, 0, xOA, xOB);
    else      l1_body(1, 0);
    __syncthreads();

    // ---- peel it=512 (rd=0): L1 -> exact f32 h1(511) into hfin
    if (!isL0) l1_final(0);
    __syncthreads();

    // ---- fc from exact f32 h1(511)
    if (t < MB * NCLS) {
        const int r = t / NCLS, c = t % NCLS;
        float acc = b_fc[c];
        const float* hf = &hfin[r][0];
        #pragma unroll 4
        for (int k = 0; k < HID; ++k)
            acc = fmaf(W_fc[c * HID + k], hf[k], acc);
        out[(b0 + r) * NCLS + c] = acc;
    }
}

extern "C" void kernel_launch(void* const* d_in, const int* in_sizes, int n_in,
                              void* d_out, int out_size, void* d_ws, size_t ws_size,
                              hipStream_t stream) {
    const float* x     = (const float*)d_in[0];
    const float* W_ih0 = (const float*)d_in[1];
    const float* W_hh0 = (const float*)d_in[2];
    const float* b_ih0 = (const float*)d_in[3];
    const float* b_hh0 = (const float*)d_in[4];
    const float* W_ih1 = (const float*)d_in[5];
    const float* W_hh1 = (const float*)d_in[6];
    const float* b_ih1 = (const float*)d_in[7];
    const float* b_hh1 = (const float*)d_in[8];
    const float* W_fc  = (const float*)d_in[9];
    const float* b_fc  = (const float*)d_in[10];
    float* out = (float*)d_out;

    rnn2_i8x<<<dim3(512 / MB), dim3(1024), 0, stream>>>(
        x, W_ih0, W_hh0, b_ih0, b_hh0, W_ih1, W_hh1, b_ih1, b_hh1, W_fc, b_fc, out);
}

// Round 19
// 329.087 us; speedup vs baseline: 1.1301x; 1.1301x over previous
//
#include <hip/hip_runtime.h>

#define SEQ   512
#define IN    28
#define HID   128
#define NCLS  10
#define MB    16        // batch rows per block -> 32 blocks
#define PCH   144       // LDS pitch bytes for i8 h arrays (16B-aligned; 2-way bank alias = free)
#define MAGICF 12582912.0f   // 1.5 * 2^23

typedef __attribute__((ext_vector_type(4))) int   i32x4;
typedef __attribute__((ext_vector_type(4))) float f32x4;
typedef __attribute__((ext_vector_type(8))) short short8v;

// h = a/127 ; W = wa/1024 + wb/262144
// wa*a scale 1/(127*1024)=SH_AA ; wb*a scale SH_AA/256
#define SH_AA (1.0f/130048.0f)

__device__ __forceinline__ unsigned short f2bf(float f) {
    unsigned u = __float_as_uint(f);
    return (unsigned short)((u + 0x7FFFu + ((u >> 16) & 1u)) >> 16);   // RNE
}
__device__ __forceinline__ float bf2f(unsigned short h) {
    return __uint_as_float(((unsigned)h) << 16);
}
__device__ __forceinline__ void split2(float f, unsigned short& hi, unsigned short& lo) {
    hi = f2bf(f);
    lo = f2bf(f - bf2f(hi));
}
__device__ __forceinline__ unsigned cvtpk(float a, float b) {
    unsigned r;
    asm("v_cvt_pk_bf16_f32 %0, %1, %2" : "=v"(r) : "v"(a), "v"(b));
    return r;
}
__device__ __forceinline__ float fast_tanh(float x) {
    float e = __expf(2.0f * x);
    return 1.0f - 2.0f * __builtin_amdgcn_rcpf(e + 1.0f);
}
__device__ __forceinline__ f32x4 mfma_bf(short8v a, short8v b, f32x4 c) {
    return __builtin_amdgcn_mfma_f32_16x16x32_bf16(a, b, c, 0, 0, 0);
}
__device__ __forceinline__ i32x4 mfma_i8(i32x4 a, i32x4 b, i32x4 c) {
    return __builtin_amdgcn_mfma_i32_16x16x64_i8(a, b, c, 0, 0, 0);
}
__device__ __forceinline__ void quantW(float wv, signed char& qa, signed char& qb) {
    int a = (int)rintf(wv * 1024.0f);
    float r = fmaf((float)a, -1.0f / 1024.0f, wv);
    int b = (int)rintf(r * 262144.0f);
    b = b > 127 ? 127 : (b < -127 ? -127 : b);
    qa = (signed char)a;
    qb = (signed char)b;
}
// 1-term magic quantize: 4 tanh outputs -> packed signed bytes (a = rne(t*127))
__device__ __forceinline__ unsigned quant4a(float t0, float t1, float t2, float t3) {
    unsigned u0 = __float_as_uint(fmaf(t0, 127.0f, MAGICF));
    unsigned u1 = __float_as_uint(fmaf(t1, 127.0f, MAGICF));
    unsigned u2 = __float_as_uint(fmaf(t2, 127.0f, MAGICF));
    unsigned u3 = __float_as_uint(fmaf(t3, 127.0f, MAGICF));
    return (u0 & 0xFFu) | ((u1 & 0xFFu) << 8) | ((u2 & 0xFFu) << 16) | ((u3 & 0xFFu) << 24);
}

union FragI8 { i32x4 v; signed char c[16]; };
union FragBF { short8v s; unsigned u[4]; };

__global__ __launch_bounds__(1024)
void rnn2_i8t(const float* __restrict__ x,
              const float* __restrict__ W_ih0, const float* __restrict__ W_hh0,
              const float* __restrict__ b_ih0, const float* __restrict__ b_hh0,
              const float* __restrict__ W_ih1, const float* __restrict__ W_hh1,
              const float* __restrict__ b_ih1, const float* __restrict__ b_hh1,
              const float* __restrict__ W_fc,  const float* __restrict__ b_fc,
              float* __restrict__ out)
{
    // h state: [arr: 0=h0 1=h1][buf][batch row * PCH] (i8 a-term, [batch][unit])
    __shared__ __attribute__((aligned(16))) signed char hmem[2][2][MB * PCH];
    __shared__ float hfin[MB][HID + 4];   // exact f32 h1(511) for the fc

    const int t    = threadIdx.x;   // 0..1023 (16 waves)
    const int lane = t & 63;
    const int w    = t >> 6;        // waves 0-7: L0 (tile w); waves 8-15: L1 (tile w-8)
    const int lm   = lane & 15;
    const int lg   = lane >> 4;
    const int b0   = blockIdx.x * MB;
    const bool isL0 = (w < 8);
    const int T    = isL0 ? w : (w - 8);   // 16-unit tile
    const int j    = 16 * T + lm;          // A-row unit for weight loading

    // ---- role-specific persistent weight fragments (A-operand: A[m][k=64kt+16lg+e])
    i32x4 Wa[2][2], Wb[2][2];      // L0: [0]=Whh0 ; L1: [0]=Wih1, [1]=Whh1
    short8v WxH = {}, WxL = {};    // L0 only
    float biasv[4];

    if (isL0) {
        #pragma unroll
        for (int kt = 0; kt < 2; ++kt) {
            const float* p = W_hh0 + j * HID + 64 * kt + 16 * lg;
            FragI8 a, b;
            #pragma unroll
            for (int e = 0; e < 16; ++e) quantW(p[e], a.c[e], b.c[e]);
            Wa[0][kt] = a.v; Wb[0][kt] = b.v;
        }
        FragBF H, L;
        #pragma unroll
        for (int p = 0; p < 4; ++p) {
            const int k0 = 8 * lg + 2 * p, k1 = k0 + 1;
            float w0 = (k0 < IN) ? W_ih0[j * IN + k0] : 0.0f;
            float w1 = (k1 < IN) ? W_ih0[j * IN + k1] : 0.0f;
            unsigned short h0s, l0s, h1s, l1s;
            split2(w0, h0s, l0s);
            split2(w1, h1s, l1s);
            H.u[p] = (unsigned)h0s | ((unsigned)h1s << 16);
            L.u[p] = (unsigned)l0s | ((unsigned)l1s << 16);
        }
        WxH = H.s; WxL = L.s;
        #pragma unroll
        for (int r = 0; r < 4; ++r) {
            const int u = 16 * T + 4 * lg + r;
            biasv[r] = b_ih0[u] + b_hh0[u];
        }
    } else {
        #pragma unroll
        for (int kt = 0; kt < 2; ++kt) {
            const float* p1 = W_ih1 + j * HID + 64 * kt + 16 * lg;
            const float* p2 = W_hh1 + j * HID + 64 * kt + 16 * lg;
            FragI8 a1, q1, a2, q2;
            #pragma unroll
            for (int e = 0; e < 16; ++e) {
                quantW(p1[e], a1.c[e], q1.c[e]);
                quantW(p2[e], a2.c[e], q2.c[e]);
            }
            Wa[0][kt] = a1.v; Wb[0][kt] = q1.v;
            Wa[1][kt] = a2.v; Wb[1][kt] = q2.v;
        }
        #pragma unroll
        for (int r = 0; r < 4; ++r) {
            const int u = 16 * T + 4 * lg + r;
            biasv[r] = b_ih1[u] + b_hh1[u];
        }
    }

    // ---- zero LDS h-state (both buffers): 2304 dwords / 1024 threads
    {
        int* z = (int*)&hmem[0][0][0];
        #pragma unroll
        for (int i = 0; i < 3; ++i) {
            const int idx = t + i * 1024;
            if (idx < (int)(sizeof(hmem) / 4)) z[idx] = 0;
        }
    }

    // ---- x (L0 waves only): lane covers batch lm, k = 8lg..8lg+7
    const float* xp = x + ((size_t)(b0 + lm) * SEQ) * IN + 8 * lg;
    float4 xA = make_float4(0.f, 0.f, 0.f, 0.f), xB = xA;
    if (isL0) {
        xA = *(const float4*)xp;
        if (lg < 3) xB = *(const float4*)(xp + 4);
    }
    __syncthreads();

    const int rbase = lm * PCH + 16 * lg;
    const int wbase = lm * PCH + 16 * T + 4 * lg;
    const i32x4 z4 = {0, 0, 0, 0};

    // ---- pipelined time loop: iter it computes h0(it) [L0] and h1(it-1) [L1]; 1 barrier.
    for (int it = 0; it <= SEQ; ++it) {
        const int rd = it & 1, wr = rd ^ 1;

        if (isL0) {
            i32x4 Ba0[2];
            Ba0[0] = *(const i32x4*)&hmem[0][rd][rbase];
            Ba0[1] = *(const i32x4*)&hmem[0][rd][rbase + 64];

            // x B-frag (bf16 hi/lo via cvt_pk)
            short8v BxH, BxL;
            {
                FragBF H, L;
                H.u[0] = cvtpk(xA.x, xA.y);
                H.u[1] = cvtpk(xA.z, xA.w);
                H.u[2] = cvtpk(xB.x, xB.y);
                H.u[3] = cvtpk(xB.z, xB.w);
                L.u[0] = cvtpk(xA.x - __uint_as_float(H.u[0] << 16),
                               xA.y - __uint_as_float(H.u[0] & 0xFFFF0000u));
                L.u[1] = cvtpk(xA.z - __uint_as_float(H.u[1] << 16),
                               xA.w - __uint_as_float(H.u[1] & 0xFFFF0000u));
                L.u[2] = cvtpk(xB.x - __uint_as_float(H.u[2] << 16),
                               xB.y - __uint_as_float(H.u[2] & 0xFFFF0000u));
                L.u[3] = cvtpk(xB.z - __uint_as_float(H.u[3] << 16),
                               xB.w - __uint_as_float(H.u[3] & 0xFFFF0000u));
                BxH = H.s; BxL = L.s;
            }
            // prefetch x(it+1), clamped
            {
                const int tn = (it < SEQ - 1) ? it + 1 : SEQ - 1;
                const float* p = xp + (size_t)tn * IN;
                xA = *(const float4*)p;
                xB = (lg < 3) ? *(const float4*)(p + 4) : make_float4(0.f, 0.f, 0.f, 0.f);
            }

            f32x4 accx = {biasv[0], biasv[1], biasv[2], biasv[3]};
            accx = mfma_bf(WxH, BxH, accx);
            accx = mfma_bf(WxL, BxH, accx);
            accx = mfma_bf(WxH, BxL, accx);

            i32x4 aa = mfma_i8(Wa[0][0], Ba0[0], z4);
            aa = mfma_i8(Wa[0][1], Ba0[1], aa);
            i32x4 cr = mfma_i8(Wb[0][0], Ba0[0], z4);
            cr = mfma_i8(Wb[0][1], Ba0[1], cr);

            float t0 = fast_tanh(accx[0] + SH_AA * fmaf((float)cr[0], 1.0f / 256.0f, (float)aa[0]));
            float t1 = fast_tanh(accx[1] + SH_AA * fmaf((float)cr[1], 1.0f / 256.0f, (float)aa[1]));
            float t2 = fast_tanh(accx[2] + SH_AA * fmaf((float)cr[2], 1.0f / 256.0f, (float)aa[2]));
            float t3 = fast_tanh(accx[3] + SH_AA * fmaf((float)cr[3], 1.0f / 256.0f, (float)aa[3]));
            *(unsigned*)&hmem[0][wr][wbase] = quant4a(t0, t1, t2, t3);
        } else {
            i32x4 Ba0[2], Ba1[2];
            Ba0[0] = *(const i32x4*)&hmem[0][rd][rbase];
            Ba0[1] = *(const i32x4*)&hmem[0][rd][rbase + 64];
            Ba1[0] = *(const i32x4*)&hmem[1][rd][rbase];
            Ba1[1] = *(const i32x4*)&hmem[1][rd][rbase + 64];

            i32x4 aa = mfma_i8(Wa[0][0], Ba0[0], z4);
            aa = mfma_i8(Wa[0][1], Ba0[1], aa);
            aa = mfma_i8(Wa[1][0], Ba1[0], aa);
            aa = mfma_i8(Wa[1][1], Ba1[1], aa);
            i32x4 cr = mfma_i8(Wb[0][0], Ba0[0], z4);
            cr = mfma_i8(Wb[0][1], Ba0[1], cr);
            cr = mfma_i8(Wb[1][0], Ba1[0], cr);
            cr = mfma_i8(Wb[1][1], Ba1[1], cr);

            float t0, t1, t2, t3;
            if (it == 0) {
                t0 = t1 = t2 = t3 = 0.0f;
            } else {
                t0 = fast_tanh(biasv[0] + SH_AA * fmaf((float)cr[0], 1.0f / 256.0f, (float)aa[0]));
                t1 = fast_tanh(biasv[1] + SH_AA * fmaf((float)cr[1], 1.0f / 256.0f, (float)aa[1]));
                t2 = fast_tanh(biasv[2] + SH_AA * fmaf((float)cr[2], 1.0f / 256.0f, (float)aa[2]));
                t3 = fast_tanh(biasv[3] + SH_AA * fmaf((float)cr[3], 1.0f / 256.0f, (float)aa[3]));
            }
            *(unsigned*)&hmem[1][wr][wbase] = quant4a(t0, t1, t2, t3);
            if (it == SEQ) {   // exact f32 h1(511) for the fc
                const int u = 16 * T + 4 * lg;
                hfin[lm][u + 0] = t0;
                hfin[lm][u + 1] = t1;
                hfin[lm][u + 2] = t2;
                hfin[lm][u + 3] = t3;
            }
        }
        __syncthreads();
    }

    // ---- fc from exact f32 h1(511)
    if (t < MB * NCLS) {
        const int r = t / NCLS, c = t % NCLS;
        float acc = b_fc[c];
        const float* hf = &hfin[r][0];
        #pragma unroll 4
        for (int k = 0; k < HID; ++k)
            acc = fmaf(W_fc[c * HID + k], hf[k], acc);
        out[(b0 + r) * NCLS + c] = acc;
    }
}

extern "C" void kernel_launch(void* const* d_in, const int* in_sizes, int n_in,
                              void* d_out, int out_size, void* d_ws, size_t ws_size,
                              hipStream_t stream) {
    const float* x     = (const float*)d_in[0];
    const float* W_ih0 = (const float*)d_in[1];
    const float* W_hh0 = (const float*)d_in[2];
    const float* b_ih0 = (const float*)d_in[3];
    const float* b_hh0 = (const float*)d_in[4];
    const float* W_ih1 = (const float*)d_in[5];
    const float* W_hh1 = (const float*)d_in[6];
    const float* b_ih1 = (const float*)d_in[7];
    const float* b_hh1 = (const float*)d_in[8];
    const float* W_fc  = (const float*)d_in[9];
    const float* b_fc  = (const float*)d_in[10];
    float* out = (float*)d_out;

    rnn2_i8t<<<dim3(512 / MB), dim3(1024), 0, stream>>>(
        x, W_ih0, W_hh0, b_ih0, b_hh0, W_ih1, W_hh1, b_ih1, b_hh1, W_fc, b_fc, out);
}